// Round 1
// baseline (227.757 us; speedup 1.0000x reference)
//
#include <hip/hip_runtime.h>

// MultiHeadAttention: B=2, S=4096, E=512, H=8, D=64
// x:[2,4096,512] f32; Wv,bv,Wk,bk,Wq,bq,Wo,bo; out:[2,4096,512] f32
// Pipeline: cvt(fp32->bf16) -> QKV gemm (bf16 MFMA, scatter to per-head q/k/vt)
//           -> flash attention (MFMA 16x16x32, online softmax)
//           -> out-proj gemm -> fp32 out.

typedef __bf16 bf16x8 __attribute__((ext_vector_type(8)));
typedef float f32x4 __attribute__((ext_vector_type(4)));
typedef unsigned int u32x4 __attribute__((ext_vector_type(4)));
typedef unsigned short u16x4 __attribute__((ext_vector_type(4)));

union U8 { bf16x8 b; u32x4 q; unsigned short s[8]; };

__device__ __forceinline__ unsigned short f2bf(float f) {
    union { float f; unsigned u; } x; x.f = f;
    unsigned r = x.u + 0x7FFFu + ((x.u >> 16) & 1u);   // RNE
    return (unsigned short)(r >> 16);
}

// async global->LDS, 16B per lane. LDS dest must be wave-uniform base; HW adds lane*16.
__device__ __forceinline__ void stage16(const void* g, void* lds) {
    __builtin_amdgcn_global_load_lds(
        (const __attribute__((address_space(1))) unsigned*)g,
        (__attribute__((address_space(3))) unsigned*)lds, 16, 0, 0);
}

__device__ __forceinline__ f32x4 mfma16(bf16x8 a, bf16x8 b, f32x4 c) {
    return __builtin_amdgcn_mfma_f32_16x16x32_bf16(a, b, c, 0, 0, 0);
}

// ---------------- convert fp32 -> bf16 (x, Wq|Wk|Wv packed, Wo) ----------------
__global__ __launch_bounds__(256) void cvt_kernel(
    const float* __restrict__ x, const float* __restrict__ wq, const float* __restrict__ wk,
    const float* __restrict__ wv, const float* __restrict__ wo,
    unsigned short* __restrict__ xb, unsigned short* __restrict__ wqkv,
    unsigned short* __restrict__ wob)
{
    const int NX = 8192 * 512, NW = 512 * 512;
    const int total = NX + 4 * NW;
    for (int i = blockIdx.x * 256 + threadIdx.x; i < total; i += gridDim.x * 256) {
        if (i < NX) {
            xb[i] = f2bf(x[i]);
        } else if (i < NX + 3 * NW) {
            int j = i - NX; int p = j / NW; int r = j - p * NW;
            const float* w = (p == 0) ? wq : (p == 1) ? wk : wv;
            wqkv[j] = f2bf(w[r]);
        } else {
            int j = i - NX - 3 * NW;
            wob[j] = f2bf(wo[j]);
        }
    }
}

// ---------------- GEMM C = A @ Bw^T (+bias); A:[8192][512] bf16, Bw:[N][512] bf16 ----------------
// mode 0: N=1536 packed [Wq;Wk;Wv] -> scatter to q[bh][s][d], k[bh][s][d], vt[bh][d][s] (bf16)
// mode 1: N=512 Wo -> outf fp32 [8192][512]
__global__ __launch_bounds__(256) void gemm_bt(
    const unsigned short* __restrict__ A, const unsigned short* __restrict__ Bw, int mode,
    const float* __restrict__ bias0, const float* __restrict__ bias1, const float* __restrict__ bias2,
    unsigned short* __restrict__ qo, unsigned short* __restrict__ ko, unsigned short* __restrict__ vto,
    float* __restrict__ outf)
{
    __shared__ unsigned short Al[128 * 64];   // [m-row][k] 16KB, XOR-swizzled 16B chunks
    __shared__ unsigned short Bl[128 * 64];   // [n-row][k] 16KB
    const int tid = threadIdx.x;
    const int l = tid & 63, w = tid >> 6;
    const int l15 = l & 15, g = l >> 4;
    const int m0 = blockIdx.y * 128, n0 = blockIdx.x * 128;
    const int mo = (w >> 1) * 64, no = (w & 1) * 64;   // wave's 64x64 sub-tile
    f32x4 acc[4][4] = {};

    for (int k0 = 0; k0 < 512; k0 += 64) {
        __syncthreads();
        #pragma unroll
        for (int i = 0; i < 4; ++i) {
            int off = i * 4096 + w * 1024 + l * 16;   // byte offset in 16KB tile
            int row = off >> 7;                       // 128B rows
            int c = (l & 7) ^ (row & 7);              // fetch logical chunk c into phys slot (l&7)
            stage16(A + (m0 + row) * 512 + k0 + c * 8, (char*)Al + i * 4096 + w * 1024);
            stage16(Bw + (n0 + row) * 512 + k0 + c * 8, (char*)Bl + i * 4096 + w * 1024);
        }
        __syncthreads();
        #pragma unroll
        for (int ks = 0; ks < 2; ++ks) {
            U8 af[4];
            #pragma unroll
            for (int mt = 0; mt < 4; ++mt) {
                int row = mo + mt * 16 + l15;
                int c = (ks * 4 + g) ^ (row & 7);
                af[mt].q = *(const u32x4*)((const char*)Al + row * 128 + c * 16);
            }
            #pragma unroll
            for (int nt = 0; nt < 4; ++nt) {
                int row = no + nt * 16 + l15;
                int c = (ks * 4 + g) ^ (row & 7);
                U8 bf; bf.q = *(const u32x4*)((const char*)Bl + row * 128 + c * 16);
                #pragma unroll
                for (int mt = 0; mt < 4; ++mt)
                    acc[mt][nt] = mfma16(af[mt].b, bf.b, acc[mt][nt]);
            }
        }
    }

    if (mode == 0) {
        #pragma unroll
        for (int nt = 0; nt < 4; ++nt) {
            int n = n0 + no + nt * 16 + l15;        // 0..1535
            int proj = n >> 9, nn = n & 511;        // 0:q 1:k 2:v
            int h = nn >> 6, d = nn & 63;
            const float* bp = (proj == 0) ? bias0 : (proj == 1) ? bias1 : bias2;
            float bv_ = bp[nn];
            #pragma unroll
            for (int mt = 0; mt < 4; ++mt) {
                int m = m0 + mo + mt * 16 + g * 4;  // +r rows
                int bb = m >> 12, s = m & 4095;
                if (proj < 2) {
                    unsigned short* dst = ((proj == 0) ? qo : ko) + ((bb * 8 + h) * 4096 + s) * 64 + d;
                    #pragma unroll
                    for (int r = 0; r < 4; ++r)
                        dst[r * 64] = f2bf(acc[mt][nt][r] + bv_);
                } else {
                    u16x4 v4;
                    v4.x = f2bf(acc[mt][nt][0] + bv_);
                    v4.y = f2bf(acc[mt][nt][1] + bv_);
                    v4.z = f2bf(acc[mt][nt][2] + bv_);
                    v4.w = f2bf(acc[mt][nt][3] + bv_);
                    *(u16x4*)(vto + ((bb * 8 + h) * 64 + d) * 4096 + s) = v4;  // 4 consecutive s
                }
            }
        }
    } else {
        #pragma unroll
        for (int nt = 0; nt < 4; ++nt) {
            int n = n0 + no + nt * 16 + l15;        // 0..511
            float bv_ = bias0[n];
            #pragma unroll
            for (int mt = 0; mt < 4; ++mt) {
                int m = m0 + mo + mt * 16 + g * 4;
                float* dst = outf + (size_t)m * 512 + n;
                #pragma unroll
                for (int r = 0; r < 4; ++r)
                    dst[(size_t)r * 512] = acc[mt][nt][r] + bv_;
            }
        }
    }
}

// ---------------- flash attention ----------------
// grid 512: bh = bx>>5 (16), qb = bx&31. 4 waves x 32 q-rows = 128 q-rows/WG. KV chunk 64.
// ET = mfma(Ktile, Q^T): lane owns q-row (l&15), k = mt*16 + 4*(l>>4) + reg.
// PV: O^T = mfma(VTtile, P^T): lane owns q-row (l&15), d = dt*16 + 4*(l>>4) + reg.
__global__ __launch_bounds__(256) void attn_kernel(
    const unsigned short* __restrict__ Qg, const unsigned short* __restrict__ Kg,
    const unsigned short* __restrict__ Vtg, unsigned short* __restrict__ Og)
{
    __shared__ unsigned short Kl[64 * 64];     // [k][d] 8KB, swizzled
    __shared__ unsigned short Vl[64 * 64];     // [d][k] (V^T) 8KB, swizzled
    __shared__ unsigned short Pl[4][32 * 64];  // per-wave P [q][k] 4KB, swizzled
    const int tid = threadIdx.x;
    const int l = tid & 63, w = tid >> 6;
    const int l15 = l & 15, g = l >> 4;
    const int bh = blockIdx.x >> 5, qb = blockIdx.x & 31;
    const unsigned short* qh = Qg + bh * 4096 * 64;
    const unsigned short* kh = Kg + bh * 4096 * 64;
    const unsigned short* vh = Vtg + bh * 64 * 4096;
    const int qw = qb * 128 + w * 32;

    U8 Qf[2][2];   // [q-subtile][k-step of D=64]
    #pragma unroll
    for (int nt = 0; nt < 2; ++nt)
        #pragma unroll
        for (int ks = 0; ks < 2; ++ks)
            Qf[nt][ks].q = *(const u32x4*)(qh + (qw + nt * 16 + l15) * 64 + ks * 32 + g * 8);

    f32x4 oacc[4][2] = {};                       // [d-subtile][q-subtile]
    float mrun[2] = { -__builtin_inff(), -__builtin_inff() };
    float lrun[2] = { 0.f, 0.f };
    const float sc = 0.044194173824159216f * 1.4426950408889634f;  // 1/sqrt(512) * log2(e)

    for (int kb = 0; kb < 4096; kb += 64) {
        __syncthreads();
        #pragma unroll
        for (int i = 0; i < 2; ++i) {
            int off = i * 4096 + w * 1024 + l * 16;
            int row = off >> 7;
            int c = (l & 7) ^ (row & 7);
            stage16(kh + (kb + row) * 64 + c * 8, (char*)Kl + i * 4096 + w * 1024);
            stage16(vh + row * 4096 + kb + c * 8, (char*)Vl + i * 4096 + w * 1024);
        }
        __syncthreads();

        // ET = K @ Q^T
        f32x4 eacc[4][2];
        #pragma unroll
        for (int mt = 0; mt < 4; ++mt)
            #pragma unroll
            for (int nt = 0; nt < 2; ++nt) { f32x4 z = {0.f,0.f,0.f,0.f}; eacc[mt][nt] = z; }
        #pragma unroll
        for (int ks = 0; ks < 2; ++ks) {
            U8 kf[4];
            #pragma unroll
            for (int mt = 0; mt < 4; ++mt) {
                int row = mt * 16 + l15;
                int c = (ks * 4 + g) ^ (row & 7);
                kf[mt].q = *(const u32x4*)((const char*)Kl + row * 128 + c * 16);
            }
            #pragma unroll
            for (int nt = 0; nt < 2; ++nt)
                #pragma unroll
                for (int mt = 0; mt < 4; ++mt)
                    eacc[mt][nt] = mfma16(kf[mt].b, Qf[nt][ks].b, eacc[mt][nt]);
        }

        // online softmax per owned q-row; write P (bf16) to per-wave LDS
        #pragma unroll
        for (int nt = 0; nt < 2; ++nt) {
            float e[16];
            float cm = -__builtin_inff();
            #pragma unroll
            for (int mt = 0; mt < 4; ++mt)
                #pragma unroll
                for (int r = 0; r < 4; ++r) {
                    float v = eacc[mt][nt][r] * sc;
                    e[mt * 4 + r] = v;
                    cm = fmaxf(cm, v);
                }
            cm = fmaxf(cm, __shfl_xor(cm, 16, 64));
            cm = fmaxf(cm, __shfl_xor(cm, 32, 64));
            float mnew = fmaxf(mrun[nt], cm);
            float alpha = exp2f(mrun[nt] - mnew);
            mrun[nt] = mnew;
            float rs = 0.f;
            unsigned short pb[16];
            #pragma unroll
            for (int i2 = 0; i2 < 16; ++i2) {
                float p = exp2f(e[i2] - mnew);
                rs += p;
                pb[i2] = f2bf(p);
            }
            rs += __shfl_xor(rs, 16, 64);
            rs += __shfl_xor(rs, 32, 64);
            lrun[nt] = lrun[nt] * alpha + rs;
            #pragma unroll
            for (int dt = 0; dt < 4; ++dt)
                #pragma unroll
                for (int r = 0; r < 4; ++r) oacc[dt][nt][r] *= alpha;
            int prow = nt * 16 + l15;
            #pragma unroll
            for (int mt = 0; mt < 4; ++mt) {
                int bytein = mt * 32 + g * 8;            // k = mt*16 + g*4 + r  (4 bf16 = 8B)
                int c = (bytein >> 4) ^ (prow & 7);
                u16x4 v4;
                v4.x = pb[mt * 4 + 0]; v4.y = pb[mt * 4 + 1];
                v4.z = pb[mt * 4 + 2]; v4.w = pb[mt * 4 + 3];
                *(u16x4*)((char*)Pl[w] + prow * 128 + c * 16 + (bytein & 15)) = v4;
            }
        }

        // PV: O^T += V^T @ P^T
        #pragma unroll
        for (int ks = 0; ks < 2; ++ks) {
            U8 pf[2];
            #pragma unroll
            for (int nt = 0; nt < 2; ++nt) {
                int row = nt * 16 + l15;
                int c = (ks * 4 + g) ^ (row & 7);
                pf[nt].q = *(const u32x4*)((const char*)Pl[w] + row * 128 + c * 16);
            }
            #pragma unroll
            for (int dt = 0; dt < 4; ++dt) {
                int row = dt * 16 + l15;
                int c = (ks * 4 + g) ^ (row & 7);
                U8 vf; vf.q = *(const u32x4*)((const char*)Vl + row * 128 + c * 16);
                #pragma unroll
                for (int nt = 0; nt < 2; ++nt)
                    oacc[dt][nt] = mfma16(vf.b, pf[nt].b, oacc[dt][nt]);
            }
        }
    }

    // epilogue: O /= l, write bf16 to attn_out [b*4096+s][512] at col h*64+d
    const int b = bh >> 3, h = bh & 7;
    #pragma unroll
    for (int nt = 0; nt < 2; ++nt) {
        float inv = 1.f / lrun[nt];
        int s = qw + nt * 16 + l15;
        unsigned short* dst = Og + ((size_t)(b * 4096 + s)) * 512 + h * 64;
        #pragma unroll
        for (int dt = 0; dt < 4; ++dt) {
            u16x4 v4;
            v4.x = f2bf(oacc[dt][nt][0] * inv);
            v4.y = f2bf(oacc[dt][nt][1] * inv);
            v4.z = f2bf(oacc[dt][nt][2] * inv);
            v4.w = f2bf(oacc[dt][nt][3] * inv);
            *(u16x4*)(dst + dt * 16 + g * 4) = v4;
        }
    }
}

extern "C" void kernel_launch(void* const* d_in, const int* in_sizes, int n_in,
                              void* d_out, int out_size, void* d_ws, size_t ws_size,
                              hipStream_t stream)
{
    const float* x  = (const float*)d_in[0];
    const float* Wv = (const float*)d_in[1];
    const float* bv = (const float*)d_in[2];
    const float* Wk = (const float*)d_in[3];
    const float* bk = (const float*)d_in[4];
    const float* Wq = (const float*)d_in[5];
    const float* bq = (const float*)d_in[6];
    const float* Wo = (const float*)d_in[7];
    const float* bo = (const float*)d_in[8];
    float* out = (float*)d_out;

    char* p = (char*)d_ws;
    unsigned short* xb   = (unsigned short*)p; p += (size_t)8192 * 512 * 2;   // x bf16; reused as attn-out
    unsigned short* wqkv = (unsigned short*)p; p += (size_t)1536 * 512 * 2;
    unsigned short* wob  = (unsigned short*)p; p += (size_t)512 * 512 * 2;
    unsigned short* qa   = (unsigned short*)p; p += (size_t)16 * 4096 * 64 * 2;
    unsigned short* ka   = (unsigned short*)p; p += (size_t)16 * 4096 * 64 * 2;
    unsigned short* vta  = (unsigned short*)p; p += (size_t)16 * 4096 * 64 * 2;
    unsigned short* ao   = xb;   // xb is dead after QKV gemm

    cvt_kernel<<<20480, 256, 0, stream>>>(x, Wq, Wk, Wv, Wo, xb, wqkv, wob);

    dim3 gq(12, 64);   // N=1536, M=8192
    gemm_bt<<<gq, 256, 0, stream>>>(xb, wqkv, 0, bq, bk, bv, qa, ka, vta, nullptr);

    attn_kernel<<<512, 256, 0, stream>>>(qa, ka, vta, ao);

    dim3 go(4, 64);    // N=512, M=8192
    gemm_bt<<<go, 256, 0, stream>>>(ao, wob, 1, bo, nullptr, nullptr, nullptr, nullptr, nullptr, out);
}

// Round 2
// 187.128 us; speedup vs baseline: 1.2171x; 1.2171x over previous
//
#include <hip/hip_runtime.h>

// MultiHeadAttention: B=2, S=4096, E=512, H=8, D=64
// cvt(fp32->bf16) -> QKV gemm (q pre-scaled by log2e/sqrt(512)) ->
// flash attention (8 waves/block, in-block 2-way KV split, defer-max) ->
// out-proj gemm -> fp32 out.

typedef __bf16 bf16x8 __attribute__((ext_vector_type(8)));
typedef float f32x4 __attribute__((ext_vector_type(4)));
typedef unsigned int u32x4 __attribute__((ext_vector_type(4)));
typedef unsigned short u16x4 __attribute__((ext_vector_type(4)));
typedef unsigned int u32x2 __attribute__((ext_vector_type(2)));

union U8 { bf16x8 b; u32x4 q; unsigned short s[8]; };

__device__ __forceinline__ unsigned short f2bf(float f) {
    union { float f; unsigned u; } x; x.f = f;
    unsigned r = x.u + 0x7FFFu + ((x.u >> 16) & 1u);   // RNE
    return (unsigned short)(r >> 16);
}

// packed f32x2 -> bf16x2 (lo -> D[15:0], hi -> D[31:16])
__device__ __forceinline__ unsigned cvtpk(float lo, float hi) {
    unsigned d;
    asm("v_cvt_pk_bf16_f32 %0, %1, %2" : "=v"(d) : "v"(lo), "v"(hi));
    return d;
}

// async global->LDS, 16B per lane. LDS dest is wave-uniform base; HW adds lane*16.
__device__ __forceinline__ void stage16(const void* g, void* lds) {
    __builtin_amdgcn_global_load_lds(
        (const __attribute__((address_space(1))) unsigned*)g,
        (__attribute__((address_space(3))) unsigned*)lds, 16, 0, 0);
}

__device__ __forceinline__ f32x4 mfma16(bf16x8 a, bf16x8 b, f32x4 c) {
    return __builtin_amdgcn_mfma_f32_16x16x32_bf16(a, b, c, 0, 0, 0);
}

// ---------------- convert fp32 -> bf16 (x, Wq|Wk|Wv packed, Wo) ----------------
__global__ __launch_bounds__(256) void cvt_kernel(
    const float* __restrict__ x, const float* __restrict__ wq, const float* __restrict__ wk,
    const float* __restrict__ wv, const float* __restrict__ wo,
    unsigned short* __restrict__ xb, unsigned short* __restrict__ wqkv,
    unsigned short* __restrict__ wob)
{
    const int NX = 8192 * 512, NW = 512 * 512;
    const int total = NX + 4 * NW;
    for (int i = blockIdx.x * 256 + threadIdx.x; i < total; i += gridDim.x * 256) {
        if (i < NX) {
            xb[i] = f2bf(x[i]);
        } else if (i < NX + 3 * NW) {
            int j = i - NX; int p = j / NW; int r = j - p * NW;
            const float* w = (p == 0) ? wq : (p == 1) ? wk : wv;
            wqkv[j] = f2bf(w[r]);
        } else {
            int j = i - NX - 3 * NW;
            wob[j] = f2bf(wo[j]);
        }
    }
}

// ---------------- GEMM C = A @ Bw^T (+bias); A:[8192][512] bf16, Bw:[N][512] bf16 ----------------
// mode 0: N=1536 packed [Wq;Wk;Wv] -> q (pre-scaled by log2e/sqrt(512)), k, vt
// mode 1: N=512 Wo -> outf fp32
__global__ __launch_bounds__(256) void gemm_bt(
    const unsigned short* __restrict__ A, const unsigned short* __restrict__ Bw, int mode,
    const float* __restrict__ bias0, const float* __restrict__ bias1, const float* __restrict__ bias2,
    unsigned short* __restrict__ qo, unsigned short* __restrict__ ko, unsigned short* __restrict__ vto,
    float* __restrict__ outf)
{
    __shared__ unsigned short Al[128 * 64];   // [m-row][k] 16KB, XOR-swizzled 16B chunks
    __shared__ unsigned short Bl[128 * 64];   // [n-row][k] 16KB
    const int tid = threadIdx.x;
    const int l = tid & 63, w = tid >> 6;
    const int l15 = l & 15, g = l >> 4;
    const int m0 = blockIdx.y * 128, n0 = blockIdx.x * 128;
    const int mo = (w >> 1) * 64, no = (w & 1) * 64;   // wave's 64x64 sub-tile
    f32x4 acc[4][4] = {};

    for (int k0 = 0; k0 < 512; k0 += 64) {
        __syncthreads();
        #pragma unroll
        for (int i = 0; i < 4; ++i) {
            int off = i * 4096 + w * 1024 + l * 16;   // byte offset in 16KB tile
            int row = off >> 7;                       // 128B rows
            int c = (l & 7) ^ (row & 7);              // fetch logical chunk c into phys slot (l&7)
            stage16(A + (m0 + row) * 512 + k0 + c * 8, (char*)Al + i * 4096 + w * 1024);
            stage16(Bw + (n0 + row) * 512 + k0 + c * 8, (char*)Bl + i * 4096 + w * 1024);
        }
        __syncthreads();
        #pragma unroll
        for (int ks = 0; ks < 2; ++ks) {
            U8 af[4];
            #pragma unroll
            for (int mt = 0; mt < 4; ++mt) {
                int row = mo + mt * 16 + l15;
                int c = (ks * 4 + g) ^ (row & 7);
                af[mt].q = *(const u32x4*)((const char*)Al + row * 128 + c * 16);
            }
            #pragma unroll
            for (int nt = 0; nt < 4; ++nt) {
                int row = no + nt * 16 + l15;
                int c = (ks * 4 + g) ^ (row & 7);
                U8 bf; bf.q = *(const u32x4*)((const char*)Bl + row * 128 + c * 16);
                #pragma unroll
                for (int mt = 0; mt < 4; ++mt)
                    acc[mt][nt] = mfma16(af[mt].b, bf.b, acc[mt][nt]);
            }
        }
    }

    if (mode == 0) {
        const float QSC = 0.06375871897178588f;      // log2(e)/sqrt(512)
        #pragma unroll
        for (int nt = 0; nt < 4; ++nt) {
            int n = n0 + no + nt * 16 + l15;        // 0..1535
            int proj = n >> 9, nn = n & 511;        // 0:q 1:k 2:v
            int h = nn >> 6, d = nn & 63;
            const float* bp = (proj == 0) ? bias0 : (proj == 1) ? bias1 : bias2;
            float bv_ = bp[nn];
            #pragma unroll
            for (int mt = 0; mt < 4; ++mt) {
                int m = m0 + mo + mt * 16 + g * 4;  // +r rows
                int bb = m >> 12, s = m & 4095;
                if (proj == 0) {
                    unsigned short* dst = qo + ((bb * 8 + h) * 4096 + s) * 64 + d;
                    #pragma unroll
                    for (int r = 0; r < 4; ++r)
                        dst[r * 64] = f2bf((acc[mt][nt][r] + bv_) * QSC);
                } else if (proj == 1) {
                    unsigned short* dst = ko + ((bb * 8 + h) * 4096 + s) * 64 + d;
                    #pragma unroll
                    for (int r = 0; r < 4; ++r)
                        dst[r * 64] = f2bf(acc[mt][nt][r] + bv_);
                } else {
                    u16x4 v4;
                    v4.x = f2bf(acc[mt][nt][0] + bv_);
                    v4.y = f2bf(acc[mt][nt][1] + bv_);
                    v4.z = f2bf(acc[mt][nt][2] + bv_);
                    v4.w = f2bf(acc[mt][nt][3] + bv_);
                    *(u16x4*)(vto + ((bb * 8 + h) * 64 + d) * 4096 + s) = v4;  // 4 consecutive s
                }
            }
        }
    } else {
        #pragma unroll
        for (int nt = 0; nt < 4; ++nt) {
            int n = n0 + no + nt * 16 + l15;        // 0..511
            float bv_ = bias0[n];
            #pragma unroll
            for (int mt = 0; mt < 4; ++mt) {
                int m = m0 + mo + mt * 16 + g * 4;
                float* dst = outf + (size_t)m * 512 + n;
                #pragma unroll
                for (int r = 0; r < 4; ++r)
                    dst[(size_t)r * 512] = acc[mt][nt][r] + bv_;
            }
        }
    }
}

// ---------------- flash attention, 8 waves, in-block 2-way KV split ----------------
// grid 512. XCD swizzle: 2 heads per XCD. Block covers 128 q-rows.
// wave w: half hb=w>>2 (KV [hb*2048, hb*2048+2048)), rowgroup rg=w&3 (32 q-rows).
// LDS: [0,8K) K0 | [8K,16K) V0 | [16K,24K) K1 | [24K,32K) V1 | [32K+w*4K) P_w
// merge: O2 f32 [0,32K), ml [32K,33K) after loop.
__global__ __launch_bounds__(512, 4) void attn_kernel(
    const unsigned short* __restrict__ Qg, const unsigned short* __restrict__ Kg,
    const unsigned short* __restrict__ Vtg, unsigned short* __restrict__ Og)
{
    __shared__ __align__(16) char ldsb[65536];
    const int tid = threadIdx.x;
    const int l = tid & 63, w = tid >> 6;
    const int l15 = l & 15, g = l >> 4;
    const int hb = w >> 2, w4 = w & 3;

    // XCD swizzle: xcd = bx&7 round-robin; give each XCD 2 whole heads.
    const int xcd = blockIdx.x & 7, idx = blockIdx.x >> 3;
    const int bh = xcd * 2 + (idx >> 5), qb = idx & 31;

    const unsigned short* qh = Qg + bh * 4096 * 64;
    const unsigned short* kh = Kg + bh * 4096 * 64;
    const unsigned short* vh = Vtg + bh * 64 * 4096;
    const int qw = qb * 128 + w4 * 32;
    char* Khalf = ldsb + hb * 16384;
    char* Vhalf = Khalf + 8192;
    char* Pbase = ldsb + 32768 + w * 4096;

    U8 Qf[2][2];   // [q-subtile][k-step of D=64] (q pre-scaled to log2 domain)
    #pragma unroll
    for (int nt = 0; nt < 2; ++nt)
        #pragma unroll
        for (int ks = 0; ks < 2; ++ks)
            Qf[nt][ks].q = *(const u32x4*)(qh + (qw + nt * 16 + l15) * 64 + ks * 32 + g * 8);

    f32x4 oacc[4][2] = {};                       // [d-subtile][q-subtile]
    float mrun[2] = { -__builtin_inff(), -__builtin_inff() };
    float lrun[2] = { 0.f, 0.f };

    for (int kb = 0; kb < 2048; kb += 64) {
        const int kbase = hb * 2048 + kb;
        __syncthreads();
        #pragma unroll
        for (int jj2 = 0; jj2 < 2; ++jj2) {
            int jj = w4 + jj2 * 4;                 // 8 x 1KB pieces per 8KB tile, 4 waves/half
            int off = jj * 1024 + l * 16;
            int row = off >> 7;                    // 0..63
            int c = (l & 7) ^ (row & 7);
            stage16(kh + (kbase + row) * 64 + c * 8, Khalf + jj * 1024);
            stage16(vh + row * 4096 + kbase + c * 8, Vhalf + jj * 1024);
        }
        __syncthreads();

        // ET = K @ Q^T  (already in log2 domain)
        f32x4 eacc[4][2];
        #pragma unroll
        for (int mt = 0; mt < 4; ++mt)
            #pragma unroll
            for (int nt = 0; nt < 2; ++nt) { f32x4 z = {0.f,0.f,0.f,0.f}; eacc[mt][nt] = z; }
        #pragma unroll
        for (int ks = 0; ks < 2; ++ks) {
            U8 kf[4];
            #pragma unroll
            for (int mt = 0; mt < 4; ++mt) {
                int row = mt * 16 + l15;
                int c = (ks * 4 + g) ^ (row & 7);
                kf[mt].q = *(const u32x4*)(Khalf + row * 128 + c * 16);
            }
            #pragma unroll
            for (int nt = 0; nt < 2; ++nt)
                #pragma unroll
                for (int mt = 0; mt < 4; ++mt)
                    eacc[mt][nt] = mfma16(kf[mt].b, Qf[nt][ks].b, eacc[mt][nt]);
        }

        // online softmax (defer-max THR=8 in log2 domain), P -> per-wave LDS
        #pragma unroll
        for (int nt = 0; nt < 2; ++nt) {
            float cm = -__builtin_inff();
            #pragma unroll
            for (int mt = 0; mt < 4; ++mt)
                #pragma unroll
                for (int r = 0; r < 4; ++r)
                    cm = fmaxf(cm, eacc[mt][nt][r]);
            cm = fmaxf(cm, __shfl_xor(cm, 16, 64));
            cm = fmaxf(cm, __shfl_xor(cm, 32, 64));
            if (__any(cm > mrun[nt] + 8.f)) {       // rescale (rare after warmup)
                float mnew = fmaxf(mrun[nt], cm);
                float al = exp2f(mrun[nt] - mnew);
                lrun[nt] *= al;
                #pragma unroll
                for (int dt = 0; dt < 4; ++dt)
                    #pragma unroll
                    for (int r = 0; r < 4; ++r) oacc[dt][nt][r] *= al;
                mrun[nt] = mnew;
            }
            const float mref = mrun[nt];
            float rs = 0.f;
            #pragma unroll
            for (int mt = 0; mt < 4; ++mt)
                #pragma unroll
                for (int r = 0; r < 4; ++r) {
                    float p = exp2f(eacc[mt][nt][r] - mref);   // <= 2^8
                    eacc[mt][nt][r] = p;
                    rs += p;
                }
            rs += __shfl_xor(rs, 16, 64);
            rs += __shfl_xor(rs, 32, 64);
            lrun[nt] += rs;
            const int prow = nt * 16 + l15;
            #pragma unroll
            for (int mt = 0; mt < 4; ++mt) {        // k = mt*16 + g*4 + {0..3}
                u32x2 pw;
                pw.x = cvtpk(eacc[mt][nt][0], eacc[mt][nt][1]);
                pw.y = cvtpk(eacc[mt][nt][2], eacc[mt][nt][3]);
                int byte = mt * 32 + g * 8;
                int c = ((byte >> 4) ^ (prow & 7));
                *(u32x2*)(Pbase + prow * 128 + c * 16 + (byte & 15)) = pw;
            }
        }

        // PV: O^T += V^T @ P^T
        #pragma unroll
        for (int ks = 0; ks < 2; ++ks) {
            U8 pf[2];
            #pragma unroll
            for (int nt = 0; nt < 2; ++nt) {
                int row = nt * 16 + l15;
                int c = (ks * 4 + g) ^ (row & 7);
                pf[nt].q = *(const u32x4*)(Pbase + row * 128 + c * 16);
            }
            #pragma unroll
            for (int dt = 0; dt < 4; ++dt) {
                int row = dt * 16 + l15;
                int c = (ks * 4 + g) ^ (row & 7);
                U8 vf; vf.q = *(const u32x4*)(Vhalf + row * 128 + c * 16);
                #pragma unroll
                for (int nt = 0; nt < 2; ++nt)
                    oacc[dt][nt] = mfma16(vf.b, pf[nt].b, oacc[dt][nt]);
            }
        }
    }

    // ---- in-block merge of the two KV halves ----
    __syncthreads();
    if (w >= 4) {   // upper half: publish partials
        #pragma unroll
        for (int nt = 0; nt < 2; ++nt) {
            int row = w4 * 32 + nt * 16 + l15;      // 0..127
            #pragma unroll
            for (int dt = 0; dt < 4; ++dt)
                *(f32x4*)(ldsb + row * 256 + dt * 64 + g * 16) = oacc[dt][nt];
            if (g == 0)
                *(float2*)(ldsb + 32768 + row * 8) = make_float2(mrun[nt], lrun[nt]);
        }
    }
    __syncthreads();
    if (w < 4) {    // lower half: merge + write
        const int b = bh >> 3, h = bh & 7;
        #pragma unroll
        for (int nt = 0; nt < 2; ++nt) {
            int row = w4 * 32 + nt * 16 + l15;
            float2 ml2 = *(const float2*)(ldsb + 32768 + row * 8);
            float mfin = fmaxf(mrun[nt], ml2.x);
            float a1 = exp2f(mrun[nt] - mfin);
            float a2 = exp2f(ml2.x - mfin);
            float inv = 1.f / (a1 * lrun[nt] + a2 * ml2.y);
            float s1 = a1 * inv, s2 = a2 * inv;
            int s = qw + nt * 16 + l15;
            unsigned short* dst = Og + ((size_t)(b * 4096 + s)) * 512 + h * 64;
            #pragma unroll
            for (int dt = 0; dt < 4; ++dt) {
                f32x4 o2 = *(const f32x4*)(ldsb + row * 256 + dt * 64 + g * 16);
                u16x4 v4;
                v4.x = f2bf(oacc[dt][nt][0] * s1 + o2[0] * s2);
                v4.y = f2bf(oacc[dt][nt][1] * s1 + o2[1] * s2);
                v4.z = f2bf(oacc[dt][nt][2] * s1 + o2[2] * s2);
                v4.w = f2bf(oacc[dt][nt][3] * s1 + o2[3] * s2);
                *(u16x4*)(dst + dt * 16 + g * 4) = v4;
            }
        }
    }
}

extern "C" void kernel_launch(void* const* d_in, const int* in_sizes, int n_in,
                              void* d_out, int out_size, void* d_ws, size_t ws_size,
                              hipStream_t stream)
{
    const float* x  = (const float*)d_in[0];
    const float* Wv = (const float*)d_in[1];
    const float* bv = (const float*)d_in[2];
    const float* Wk = (const float*)d_in[3];
    const float* bk = (const float*)d_in[4];
    const float* Wq = (const float*)d_in[5];
    const float* bq = (const float*)d_in[6];
    const float* Wo = (const float*)d_in[7];
    const float* bo = (const float*)d_in[8];
    float* out = (float*)d_out;

    char* p = (char*)d_ws;
    unsigned short* xb   = (unsigned short*)p; p += (size_t)8192 * 512 * 2;   // x bf16; reused as attn-out
    unsigned short* wqkv = (unsigned short*)p; p += (size_t)1536 * 512 * 2;
    unsigned short* wob  = (unsigned short*)p; p += (size_t)512 * 512 * 2;
    unsigned short* qa   = (unsigned short*)p; p += (size_t)16 * 4096 * 64 * 2;
    unsigned short* ka   = (unsigned short*)p; p += (size_t)16 * 4096 * 64 * 2;
    unsigned short* vta  = (unsigned short*)p; p += (size_t)16 * 4096 * 64 * 2;
    unsigned short* ao   = xb;   // xb is dead after QKV gemm

    cvt_kernel<<<20480, 256, 0, stream>>>(x, Wq, Wk, Wv, Wo, xb, wqkv, wob);

    dim3 gq(12, 64);   // N=1536, M=8192
    gemm_bt<<<gq, 256, 0, stream>>>(xb, wqkv, 0, bq, bk, bv, qa, ka, vta, nullptr);

    attn_kernel<<<512, 512, 0, stream>>>(qa, ka, vta, ao);

    dim3 go(4, 64);    // N=512, M=8192
    gemm_bt<<<go, 256, 0, stream>>>(ao, wob, 1, bo, nullptr, nullptr, nullptr, nullptr, nullptr, out);
}

// Round 3
// 160.578 us; speedup vs baseline: 1.4184x; 1.1653x over previous
//
#include <hip/hip_runtime.h>

// MultiHeadAttention: B=2, S=4096, E=512, H=8, D=64
// cvt(fp32->bf16) -> QKV gemm (q pre-scaled by log2e/sqrt(512)) ->
// flash attention (8 waves, 32x32x16 MFMA, in-register P via cvt_pk+permlane32_swap,
//                  double-buffered K/V, 2-way KV split, defer-max) ->
// out-proj gemm -> fp32 out.

typedef __bf16 bf16x8 __attribute__((ext_vector_type(8)));
typedef float f32x4 __attribute__((ext_vector_type(4)));
typedef float f32x16 __attribute__((ext_vector_type(16)));
typedef unsigned int u32x4 __attribute__((ext_vector_type(4)));
typedef unsigned short u16x4 __attribute__((ext_vector_type(4)));

union U8 { bf16x8 b; u32x4 q; unsigned short s[8]; };

__device__ __forceinline__ unsigned short f2bf(float f) {
    union { float f; unsigned u; } x; x.f = f;
    unsigned r = x.u + 0x7FFFu + ((x.u >> 16) & 1u);   // RNE
    return (unsigned short)(r >> 16);
}

// packed f32x2 -> bf16x2 (lo -> D[15:0], hi -> D[31:16])
__device__ __forceinline__ unsigned cvtpk(float lo, float hi) {
    unsigned d;
    asm("v_cvt_pk_bf16_f32 %0, %1, %2" : "=v"(d) : "v"(lo), "v"(hi));
    return d;
}

// async global->LDS, 16B per lane. LDS dest is wave-uniform base; HW adds lane*16.
__device__ __forceinline__ void stage16(const void* g, void* lds) {
    __builtin_amdgcn_global_load_lds(
        (const __attribute__((address_space(1))) unsigned*)g,
        (__attribute__((address_space(3))) unsigned*)lds, 16, 0, 0);
}

__device__ __forceinline__ f32x4 mfma16(bf16x8 a, bf16x8 b, f32x4 c) {
    return __builtin_amdgcn_mfma_f32_16x16x32_bf16(a, b, c, 0, 0, 0);
}
__device__ __forceinline__ f32x16 mfma32(bf16x8 a, bf16x8 b, f32x16 c) {
    return __builtin_amdgcn_mfma_f32_32x32x16_bf16(a, b, c, 0, 0, 0);
}

// ---------------- convert fp32 -> bf16 (x, Wq|Wk|Wv packed, Wo) ----------------
__global__ __launch_bounds__(256) void cvt_kernel(
    const float* __restrict__ x, const float* __restrict__ wq, const float* __restrict__ wk,
    const float* __restrict__ wv, const float* __restrict__ wo,
    unsigned short* __restrict__ xb, unsigned short* __restrict__ wqkv,
    unsigned short* __restrict__ wob)
{
    const int NX = 8192 * 512, NW = 512 * 512;
    const int total = NX + 4 * NW;
    for (int i = blockIdx.x * 256 + threadIdx.x; i < total; i += gridDim.x * 256) {
        if (i < NX) {
            xb[i] = f2bf(x[i]);
        } else if (i < NX + 3 * NW) {
            int j = i - NX; int p = j / NW; int r = j - p * NW;
            const float* w = (p == 0) ? wq : (p == 1) ? wk : wv;
            wqkv[j] = f2bf(w[r]);
        } else {
            int j = i - NX - 3 * NW;
            wob[j] = f2bf(wo[j]);
        }
    }
}

// ---------------- GEMM C = A @ Bw^T (+bias); A:[8192][512] bf16, Bw:[N][512] bf16 ----------------
// mode 0: N=1536 packed [Wq;Wk;Wv] -> q (pre-scaled by log2e/sqrt(512)), k, vt
// mode 1: N=512 Wo -> outf fp32
__global__ __launch_bounds__(256) void gemm_bt(
    const unsigned short* __restrict__ A, const unsigned short* __restrict__ Bw, int mode,
    const float* __restrict__ bias0, const float* __restrict__ bias1, const float* __restrict__ bias2,
    unsigned short* __restrict__ qo, unsigned short* __restrict__ ko, unsigned short* __restrict__ vto,
    float* __restrict__ outf)
{
    __shared__ unsigned short Al[128 * 64];   // [m-row][k] 16KB, XOR-swizzled 16B chunks
    __shared__ unsigned short Bl[128 * 64];   // [n-row][k] 16KB
    const int tid = threadIdx.x;
    const int l = tid & 63, w = tid >> 6;
    const int l15 = l & 15, g = l >> 4;
    const int m0 = blockIdx.y * 128, n0 = blockIdx.x * 128;
    const int mo = (w >> 1) * 64, no = (w & 1) * 64;   // wave's 64x64 sub-tile
    f32x4 acc[4][4] = {};

    for (int k0 = 0; k0 < 512; k0 += 64) {
        __syncthreads();
        #pragma unroll
        for (int i = 0; i < 4; ++i) {
            int off = i * 4096 + w * 1024 + l * 16;   // byte offset in 16KB tile
            int row = off >> 7;                       // 128B rows
            int c = (l & 7) ^ (row & 7);              // fetch logical chunk c into phys slot (l&7)
            stage16(A + (m0 + row) * 512 + k0 + c * 8, (char*)Al + i * 4096 + w * 1024);
            stage16(Bw + (n0 + row) * 512 + k0 + c * 8, (char*)Bl + i * 4096 + w * 1024);
        }
        __syncthreads();
        #pragma unroll
        for (int ks = 0; ks < 2; ++ks) {
            U8 af[4];
            #pragma unroll
            for (int mt = 0; mt < 4; ++mt) {
                int row = mo + mt * 16 + l15;
                int c = (ks * 4 + g) ^ (row & 7);
                af[mt].q = *(const u32x4*)((const char*)Al + row * 128 + c * 16);
            }
            #pragma unroll
            for (int nt = 0; nt < 4; ++nt) {
                int row = no + nt * 16 + l15;
                int c = (ks * 4 + g) ^ (row & 7);
                U8 bf; bf.q = *(const u32x4*)((const char*)Bl + row * 128 + c * 16);
                #pragma unroll
                for (int mt = 0; mt < 4; ++mt)
                    acc[mt][nt] = mfma16(af[mt].b, bf.b, acc[mt][nt]);
            }
        }
    }

    if (mode == 0) {
        const float QSC = 0.06375871897178588f;      // log2(e)/sqrt(512)
        #pragma unroll
        for (int nt = 0; nt < 4; ++nt) {
            int n = n0 + no + nt * 16 + l15;        // 0..1535
            int proj = n >> 9, nn = n & 511;        // 0:q 1:k 2:v
            int h = nn >> 6, d = nn & 63;
            const float* bp = (proj == 0) ? bias0 : (proj == 1) ? bias1 : bias2;
            float bv_ = bp[nn];
            #pragma unroll
            for (int mt = 0; mt < 4; ++mt) {
                int m = m0 + mo + mt * 16 + g * 4;  // +r rows
                int bb = m >> 12, s = m & 4095;
                if (proj == 0) {
                    unsigned short* dst = qo + ((bb * 8 + h) * 4096 + s) * 64 + d;
                    #pragma unroll
                    for (int r = 0; r < 4; ++r)
                        dst[r * 64] = f2bf((acc[mt][nt][r] + bv_) * QSC);
                } else if (proj == 1) {
                    unsigned short* dst = ko + ((bb * 8 + h) * 4096 + s) * 64 + d;
                    #pragma unroll
                    for (int r = 0; r < 4; ++r)
                        dst[r * 64] = f2bf(acc[mt][nt][r] + bv_);
                } else {
                    u16x4 v4;
                    v4.x = f2bf(acc[mt][nt][0] + bv_);
                    v4.y = f2bf(acc[mt][nt][1] + bv_);
                    v4.z = f2bf(acc[mt][nt][2] + bv_);
                    v4.w = f2bf(acc[mt][nt][3] + bv_);
                    *(u16x4*)(vto + ((bb * 8 + h) * 64 + d) * 4096 + s) = v4;  // 4 consecutive s
                }
            }
        }
    } else {
        #pragma unroll
        for (int nt = 0; nt < 4; ++nt) {
            int n = n0 + no + nt * 16 + l15;        // 0..511
            float bv_ = bias0[n];
            #pragma unroll
            for (int mt = 0; mt < 4; ++mt) {
                int m = m0 + mo + mt * 16 + g * 4;
                float* dst = outf + (size_t)m * 512 + n;
                #pragma unroll
                for (int r = 0; r < 4; ++r)
                    dst[(size_t)r * 512] = acc[mt][nt][r] + bv_;
            }
        }
    }
}

// ---------------- flash attention: 8 waves, 32x32x16, reg-resident P ----------------
// grid 512. wave w: half hb=w>>2 (KV range [hb*2048,+2048)), q-group w4=w&3 (32 q-rows).
// Lane owns q-col l&31 (k/d split across lane pair l, l^32).
// LDS: double buffer [t&1]*32K + hb*16K: K tile 8KB | V^T tile 8KB. Merge reuses [0,33K).
__global__ __launch_bounds__(512, 4) void attn_kernel(
    const unsigned short* __restrict__ Qg, const unsigned short* __restrict__ Kg,
    const unsigned short* __restrict__ Vtg, unsigned short* __restrict__ Og)
{
    __shared__ __align__(16) char ldsb[65536];
    const int tid = threadIdx.x;
    const int l = tid & 63, w = tid >> 6;
    const int l31 = l & 31, hi = l >> 5;
    const int hb = w >> 2, w4 = w & 3;

    // XCD swizzle: 2 whole heads per XCD.
    const int xcd = blockIdx.x & 7, idx = blockIdx.x >> 3;
    const int bh = xcd * 2 + (idx >> 5), qb = idx & 31;

    const unsigned short* qh = Qg + bh * 4096 * 64;
    const unsigned short* kh = Kg + bh * 4096 * 64;
    const unsigned short* vh = Vtg + bh * 64 * 4096;
    const int qw = qb * 128 + w4 * 32;

    // Q B-frags (log2-domain pre-scaled): Qf[ds] elem i = Q[qw+l31][ds*16 + 8*hi + i]
    U8 Qf[4];
    #pragma unroll
    for (int ds_ = 0; ds_ < 4; ++ds_)
        Qf[ds_].q = *(const u32x4*)(qh + (qw + l31) * 64 + ds_ * 16 + hi * 8);

    f32x16 oacc[2] = {};   // O^T[d = dt*32 + crow][q = l31]
    float mrun = -__builtin_inff();
    float lrun = 0.f;

    // prologue: stage chunk 0 into buf 0
    {
        char* nxt = ldsb + hb * 16384;
        const int kbase = hb * 2048;
        #pragma unroll
        for (int jj2 = 0; jj2 < 2; ++jj2) {
            int jj = w4 + jj2 * 4;
            int row = jj * 8 + (l >> 3);
            int c = (l & 7) ^ (row & 7);
            stage16(kh + (kbase + row) * 64 + c * 8, nxt + jj * 1024);
            stage16(vh + row * 4096 + kbase + c * 8, nxt + 8192 + jj * 1024);
        }
    }
    __syncthreads();

    for (int t = 0; t < 32; ++t) {
        char* curb = ldsb + (t & 1) * 32768 + hb * 16384;
        if (t < 31) {   // stage next chunk into other buffer (latency hidden under compute)
            char* nxt = ldsb + ((t + 1) & 1) * 32768 + hb * 16384;
            const int kbase = hb * 2048 + (t + 1) * 64;
            #pragma unroll
            for (int jj2 = 0; jj2 < 2; ++jj2) {
                int jj = w4 + jj2 * 4;
                int row = jj * 8 + (l >> 3);
                int c = (l & 7) ^ (row & 7);
                stage16(kh + (kbase + row) * 64 + c * 8, nxt + jj * 1024);
                stage16(vh + row * 4096 + kbase + c * 8, nxt + 8192 + jj * 1024);
            }
        }

        // ET[k][q] = K @ Q^T   (k = mt*32 + crow(reg,hi), q = l31)
        f32x16 et[2];
        {
            f32x16 z = {};
            et[0] = z; et[1] = z;
        }
        __builtin_amdgcn_s_setprio(1);
        #pragma unroll
        for (int mt = 0; mt < 2; ++mt) {
            const char* base = curb + (mt * 32 + l31) * 128;
            #pragma unroll
            for (int ds_ = 0; ds_ < 4; ++ds_) {
                int c = (ds_ * 2 + hi) ^ (l & 7);
                U8 kf; kf.q = *(const u32x4*)(base + c * 16);
                et[mt] = mfma32(kf.b, Qf[ds_].b, et[mt]);
            }
        }
        __builtin_amdgcn_s_setprio(0);

        // online softmax in log2 domain, defer-max THR=8
        float cm = et[0][0];
        #pragma unroll
        for (int mt = 0; mt < 2; ++mt)
            #pragma unroll
            for (int r = 0; r < 16; ++r)
                cm = fmaxf(cm, et[mt][r]);
        cm = fmaxf(cm, __shfl_xor(cm, 32, 64));
        if (__any(cm > mrun + 8.f)) {
            float mnew = fmaxf(mrun, cm);
            float al = exp2f(mrun - mnew);
            lrun *= al;
            #pragma unroll
            for (int dt = 0; dt < 2; ++dt)
                #pragma unroll
                for (int r = 0; r < 16; ++r)
                    oacc[dt][r] *= al;
            mrun = mnew;
        }
        float rs = 0.f;
        #pragma unroll
        for (int mt = 0; mt < 2; ++mt)
            #pragma unroll
            for (int r = 0; r < 16; ++r) {
                float p = exp2f(et[mt][r] - mrun);   // <= 2^8
                et[mt][r] = p;
                rs += p;
            }
        rs += __shfl_xor(rs, 32, 64);
        lrun += rs;

        // pack P into PV B-frags: pa[ks] elem i = P[k=ks*16+8*hi+i][q=l31]
        u32x4 pa[4];
        #pragma unroll
        for (int mt = 0; mt < 2; ++mt)
            #pragma unroll
            for (int h2 = 0; h2 < 2; ++h2) {
                int r0 = h2 * 8;
                unsigned X0 = cvtpk(et[mt][r0 + 0], et[mt][r0 + 1]);
                unsigned X1 = cvtpk(et[mt][r0 + 2], et[mt][r0 + 3]);
                unsigned Y0 = cvtpk(et[mt][r0 + 4], et[mt][r0 + 5]);
                unsigned Y1 = cvtpk(et[mt][r0 + 6], et[mt][r0 + 7]);
                asm volatile("v_permlane32_swap_b32 %0, %1" : "+v"(X0), "+v"(Y0));
                asm volatile("v_permlane32_swap_b32 %0, %1" : "+v"(X1), "+v"(Y1));
                u32x4 t4; t4.x = X0; t4.y = X1; t4.z = Y0; t4.w = Y1;
                pa[mt * 2 + h2] = t4;
            }

        // PV: O^T += V^T @ P^T
        __builtin_amdgcn_s_setprio(1);
        #pragma unroll
        for (int dt = 0; dt < 2; ++dt) {
            const char* base = curb + 8192 + (dt * 32 + l31) * 128;
            #pragma unroll
            for (int ks = 0; ks < 4; ++ks) {
                int c = (ks * 2 + hi) ^ (l & 7);
                U8 vf; vf.q = *(const u32x4*)(base + c * 16);
                U8 pb_; pb_.q = pa[ks];
                oacc[dt] = mfma32(vf.b, pb_.b, oacc[dt]);
            }
        }
        __builtin_amdgcn_s_setprio(0);
        __syncthreads();
    }

    // ---- in-block merge of the two KV halves ----
    if (w >= 4) {   // upper half publishes partials; per-lane 128B, chunk-XOR swizzled
        char* ob = ldsb + (w4 * 64 + l) * 128;
        #pragma unroll
        for (int dt = 0; dt < 2; ++dt)
            #pragma unroll
            for (int j = 0; j < 4; ++j) {
                int c = (dt * 4 + j) ^ (l & 7);
                f32x4 v4;
                v4[0] = oacc[dt][j * 4 + 0]; v4[1] = oacc[dt][j * 4 + 1];
                v4[2] = oacc[dt][j * 4 + 2]; v4[3] = oacc[dt][j * 4 + 3];
                *(f32x4*)(ob + c * 16) = v4;
            }
        if (hi == 0)
            *(float2*)(ldsb + 32768 + (w4 * 32 + l31) * 8) = make_float2(mrun, lrun);
    }
    __syncthreads();
    if (w < 4) {    // lower half merges + writes
        float2 ml2 = *(const float2*)(ldsb + 32768 + (w4 * 32 + l31) * 8);
        float mfin = fmaxf(mrun, ml2.x);
        float a1 = exp2f(mrun - mfin), a2 = exp2f(ml2.x - mfin);
        float inv = 1.f / (a1 * lrun + a2 * ml2.y);
        float s1 = a1 * inv, s2 = a2 * inv;
        const int b = bh >> 3, h = bh & 7;
        const int s = qw + l31;
        unsigned short* dst = Og + ((size_t)(b * 4096 + s)) * 512 + h * 64;
        const char* ob = ldsb + (w4 * 64 + l) * 128;
        #pragma unroll
        for (int dt = 0; dt < 2; ++dt)
            #pragma unroll
            for (int j = 0; j < 4; ++j) {
                int c = (dt * 4 + j) ^ (l & 7);
                f32x4 o2 = *(const f32x4*)(ob + c * 16);
                int d0 = dt * 32 + j * 8 + hi * 4;
                u16x4 v4;
                v4.x = f2bf(oacc[dt][j * 4 + 0] * s1 + o2[0] * s2);
                v4.y = f2bf(oacc[dt][j * 4 + 1] * s1 + o2[1] * s2);
                v4.z = f2bf(oacc[dt][j * 4 + 2] * s1 + o2[2] * s2);
                v4.w = f2bf(oacc[dt][j * 4 + 3] * s1 + o2[3] * s2);
                *(u16x4*)(dst + d0) = v4;
            }
    }
}

extern "C" void kernel_launch(void* const* d_in, const int* in_sizes, int n_in,
                              void* d_out, int out_size, void* d_ws, size_t ws_size,
                              hipStream_t stream)
{
    const float* x  = (const float*)d_in[0];
    const float* Wv = (const float*)d_in[1];
    const float* bv = (const float*)d_in[2];
    const float* Wk = (const float*)d_in[3];
    const float* bk = (const float*)d_in[4];
    const float* Wq = (const float*)d_in[5];
    const float* bq = (const float*)d_in[6];
    const float* Wo = (const float*)d_in[7];
    const float* bo = (const float*)d_in[8];
    float* out = (float*)d_out;

    char* p = (char*)d_ws;
    unsigned short* xb   = (unsigned short*)p; p += (size_t)8192 * 512 * 2;   // x bf16; reused as attn-out
    unsigned short* wqkv = (unsigned short*)p; p += (size_t)1536 * 512 * 2;
    unsigned short* wob  = (unsigned short*)p; p += (size_t)512 * 512 * 2;
    unsigned short* qa   = (unsigned short*)p; p += (size_t)16 * 4096 * 64 * 2;
    unsigned short* ka   = (unsigned short*)p; p += (size_t)16 * 4096 * 64 * 2;
    unsigned short* vta  = (unsigned short*)p; p += (size_t)16 * 4096 * 64 * 2;
    unsigned short* ao   = xb;   // xb is dead after QKV gemm

    cvt_kernel<<<20480, 256, 0, stream>>>(x, Wq, Wk, Wv, Wo, xb, wqkv, wob);

    dim3 gq(12, 64);   // N=1536, M=8192
    gemm_bt<<<gq, 256, 0, stream>>>(xb, wqkv, 0, bq, bk, bv, qa, ka, vta, nullptr);

    attn_kernel<<<512, 512, 0, stream>>>(qa, ka, vta, ao);

    dim3 go(4, 64);    // N=512, M=8192
    gemm_bt<<<go, 256, 0, stream>>>(ao, wob, 1, bo, nullptr, nullptr, nullptr, nullptr, nullptr, out);
}